// Round 6
// baseline (1559.914 us; speedup 1.0000x reference)
//
#include <hip/hip_runtime.h>

#define HID 256
#define NB 1024
#define NACT 16

typedef __bf16 bf16x8 __attribute__((ext_vector_type(8)));
typedef float  f32x4  __attribute__((ext_vector_type(4)));

// LDS map (80 KB total -> 2 blocks/CU)
#define HA_LO  32768            // lo half of hA
#define WT_OFF 65536            // 16 KB weight tile (single buffer, reg-prefetched)
#define LDS_TOT 81920
// overlays inside the Wt region (only live between kloops):
//   Sp  f32[1024] @ WT_OFF        (4 KB)
//   Sf  f32[256]  @ WT_OFF+4096   (1 KB)
//   Tp  f32[512]  @ WT_OFF+8192   (2 KB)
//   Dp  f32[2048] @ WT_OFF        (8 KB, decoder partials)

#define NWA (256*1536)
#define NWB (256*768)
#define NWD (16*768)
#define NWC (256*256)

__device__ __forceinline__ unsigned short f2bf(float x) {
    union { float f; unsigned u; } v; v.f = x;
    unsigned r = v.u + 0x7fff + ((v.u >> 16) & 1);
    return (unsigned short)(r >> 16);
}
__device__ __forceinline__ float bf2f(unsigned short b) {
    union { float f; unsigned u; } v; v.u = ((unsigned)b) << 16;
    return v.f;
}

// ---- prep: WA[256][1536]=[W1h0 stack|Aw stack]; WB[256][768]=W2 stack;
//            WD[16][768]=Wd stack; Wc f32 = inv*W1c ----
__global__ __launch_bounds__(256) void prep_k(const float* __restrict__ W1,
                                              const float* __restrict__ W2,
                                              const float* __restrict__ Wd,
                                              unsigned short* __restrict__ WA,
                                              unsigned short* __restrict__ WB,
                                              unsigned short* __restrict__ WD,
                                              float* __restrict__ Wc) {
    int i = blockIdx.x * 256 + threadIdx.x;
    const float inv = 1.0f / 63.0f;
    if (i < NWA) {
        int n = i / 1536, k = i % 1536;
        float val; int r;
        if (k < 768) { r = k >> 8; int ks = k & 255; val = W1[(512 + ks) * HID + n]; }
        else { int kk = k - 768; r = kk >> 8; int ks = kk & 255;
               val = W1[ks * HID + n] - inv * W1[(256 + ks) * HID + n]; }
        unsigned short hi = f2bf(val);
        WA[i] = (r == 1) ? f2bf(val - bf2f(hi)) : hi;
    } else if (i < NWA + NWB) {
        int j = i - NWA;
        int n = j / 768, k = j % 768;
        int r = k >> 8, ks = k & 255;
        float val = W2[ks * HID + n];
        unsigned short hi = f2bf(val);
        WB[j] = (r == 1) ? f2bf(val - bf2f(hi)) : hi;
    } else if (i < NWA + NWB + NWD) {
        int j = i - NWA - NWB;
        int n = j / 768, kp = j % 768;
        int r = kp >> 8, ks = kp & 255;
        float val = Wd[ks * NACT + n];
        unsigned short hi = f2bf(val);
        WD[j] = (r == 1) ? f2bf(val - bf2f(hi)) : hi;
    } else {
        int j = i - NWA - NWB - NWD;
        if (j < NWC) {
            int k = j >> 8, n = j & 255;
            Wc[j] = inv * W1[(256 + k) * HID + n];
        }
    }
}

// ---- BK=32 K-loop with register-prefetch of the next weight tile ----
// Per t: [WAR barrier; ds_write staged tile; issue loads t+1; RAW barrier; MFMA].
// Global-load latency hides under the MFMA phase + barriers of the previous t.
template<int LD>
__device__ __forceinline__ void kloop(const unsigned short* __restrict__ W,
                                      int kstart, int nk, char* hA, char* Wt,
                                      f32x4 (&acc)[2][4],
                                      int tid, int wm, int wn, int l15, int g)
{
    const int rxA = (l15 & 7) << 4;
    const int rowb0 = (wm * 32 + l15) * 512;
    const int rowb1 = rowb0 + 16 * 512;
    const int c0 = tid, c1 = 512 + tid;
    const int n0 = c0 >> 2, ss0 = (c0 & 3) ^ ((n0 >> 1) & 3);
    const int n1 = c1 >> 2, ss1 = (c1 & 3) ^ ((n1 >> 1) & 3);
    const unsigned short* p0 = W + (size_t)n0 * LD + kstart + ss0 * 8;
    const unsigned short* p1 = W + (size_t)n1 * LD + kstart + ss1 * 8;
    uint4 st0 = *(const uint4*)p0;
    uint4 st1 = *(const uint4*)p1;
    for (int t = 0; t < nk; ++t) {
        __syncthreads();                       // WAR: Wt free (also orders vs caller)
        *(uint4*)(Wt + c0 * 16) = st0;
        *(uint4*)(Wt + c1 * 16) = st1;
        if (t + 1 < nk) {                      // issue next tile -> regs (in flight
            st0 = *(const uint4*)(p0 + (t + 1) * 32);   //  through MFMA phase)
            st1 = *(const uint4*)(p1 + (t + 1) * 32);
        }
        __syncthreads();                       // RAW: Wt ready
        const int k0 = kstart + t * 32;
        const int reg = (k0 >> 8) % 3;
        const int aoff = (reg == 2) ? HA_LO : 0;
        const int cb = (((k0 & 255) * 2) + g * 16) ^ rxA;
        bf16x8 a0 = *(const bf16x8*)(hA + aoff + rowb0 + cb);
        bf16x8 a1 = *(const bf16x8*)(hA + aoff + rowb1 + cb);
        #pragma unroll
        for (int nt = 0; nt < 4; ++nt) {
            int nn = wn * 64 + nt * 16 + l15;
            int off = nn * 64 + ((g ^ ((nn >> 1) & 3)) << 4);
            bf16x8 bv = *(const bf16x8*)(Wt + off);
            acc[0][nt] = __builtin_amdgcn_mfma_f32_16x16x32_bf16(a0, bv, acc[0][nt], 0, 0, 0);
            acc[1][nt] = __builtin_amdgcn_mfma_f32_16x16x32_bf16(a1, bv, acc[1][nt], 0, 0, 0);
        }
    }
}

// ---- whole network, one batch per block ----
__global__ __launch_bounds__(512, 2) void fused_all(
    const int* __restrict__ ids, const float* __restrict__ emb,
    const unsigned short* __restrict__ WA, const unsigned short* __restrict__ WB,
    const unsigned short* __restrict__ WD, const float* __restrict__ Wc,
    const float* __restrict__ b1, const float* __restrict__ b2,
    const float* __restrict__ bd, float* __restrict__ out)
{
    __shared__ __align__(16) char lds[LDS_TOT];
    const int tid = threadIdx.x;
    const int lane = tid & 63;
    const int w = tid >> 6;
    const int wm = w >> 2, wn = w & 3;
    const int l15 = lane & 15, g = lane >> 4;
    const size_t rowbase = (size_t)blockIdx.x * 64;
    char* hA = lds;
    char* Wt = lds + WT_OFF;
    float* Sp = (float*)(lds + WT_OFF);
    float* Sf = (float*)(lds + WT_OFF + 4096);
    float* Tp = (float*)(lds + WT_OFF + 8192);
    float* Dp = (float*)(lds + WT_OFF);

    // ---- stage h0 = emb[ids] -> split hi/lo, XOR-swizzled ----
    {
        int r = tid >> 3, c0 = (tid & 7) * 32;
        int rx = (r & 7) << 4;
        const float4* src = (const float4*)(emb + (size_t)ids[rowbase + r] * HID + c0);
        char* dh = hA + r * 512;
        #pragma unroll
        for (int j = 0; j < 8; ++j) {
            float4 v = src[j];
            unsigned short h0 = f2bf(v.x), h1 = f2bf(v.y), h2 = f2bf(v.z), h3 = f2bf(v.w);
            unsigned short q0 = f2bf(v.x - bf2f(h0)), q1 = f2bf(v.y - bf2f(h1)),
                           q2 = f2bf(v.z - bf2f(h2)), q3 = f2bf(v.w - bf2f(h3));
            int byte = ((c0 + j * 4) * 2) ^ rx;
            *(uint2*)(dh + byte) = make_uint2((unsigned)h0 | ((unsigned)h1 << 16),
                                             (unsigned)h2 | ((unsigned)h3 << 16));
            *(uint2*)(dh + HA_LO + byte) = make_uint2((unsigned)q0 | ((unsigned)q1 << 16),
                                                      (unsigned)q2 | ((unsigned)q3 << 16));
        }
    }

    // ---- S/T: T[col] = (sum_rows h) @ Wc, fully parallel, in Wt overlay ----
    auto ST = [&]() {
        __syncthreads();                 // hA writes visible; Wt region free
        {
            int ww = tid & 127, gq = tid >> 7;
            float s0 = 0.f, s1 = 0.f;
            #pragma unroll 4
            for (int r = gq * 16; r < gq * 16 + 16; ++r) {
                int byte = r * 512 + ((ww * 4) ^ ((r & 7) << 4));
                unsigned vh = *(const unsigned*)(hA + byte);
                unsigned vl = *(const unsigned*)(hA + HA_LO + byte);
                s0 += bf2f((unsigned short)vh) + bf2f((unsigned short)vl);
                s1 += bf2f((unsigned short)(vh >> 16)) + bf2f((unsigned short)(vl >> 16));
            }
            Sp[gq * 256 + ww * 2] = s0;
            Sp[gq * 256 + ww * 2 + 1] = s1;
        }
        __syncthreads();
        if (tid < 256) Sf[tid] = (Sp[tid] + Sp[256 + tid]) + (Sp[512 + tid] + Sp[768 + tid]);
        __syncthreads();
        {
            int n = tid & 255, kh = tid >> 8;
            float a = 0.f;
            #pragma unroll 8
            for (int k = kh * 128; k < kh * 128 + 128; ++k)
                a += Sf[k] * Wc[(k << 8) + n];
            Tp[kh * 256 + n] = a;
        }
        __syncthreads();                 // Tp visible for tv read
    };

    ST();
    float tv[4];
    #pragma unroll
    for (int nt = 0; nt < 4; ++nt) {
        int col = wn * 64 + nt * 16 + l15;
        tv[nt] = Tp[col] + Tp[256 + col];
    }
    // next kloop's leading barrier orders tv reads vs Wt overwrite

    f32x4 acc[2][4], u0r[2][4];
    #pragma unroll
    for (int mt = 0; mt < 2; ++mt)
        #pragma unroll
        for (int nt = 0; nt < 4; ++nt) acc[mt][nt] = (f32x4){0.f, 0.f, 0.f, 0.f};

    for (int s = 0; s < 4; ++s) {
        // ---- phase A ----
        if (s == 0) {
            kloop<1536>(WA, 0, 24, hA, Wt, acc, tid, wm, wn, l15, g);   // h0 @ W1h0
            #pragma unroll
            for (int nt = 0; nt < 4; ++nt) {
                float bb = b1[wn * 64 + nt * 16 + l15];
                #pragma unroll
                for (int mt = 0; mt < 2; ++mt)
                    #pragma unroll
                    for (int q = 0; q < 4; ++q) {
                        u0r[mt][nt][q] = acc[mt][nt][q] + bb;
                        acc[mt][nt][q] = 0.f;
                    }
            }
        }
        kloop<1536>(WA, 768, 24, hA, Wt, acc, tid, wm, wn, l15, g);     // h @ Aw

        // ---- epilogue A: act = relu(acc + T + u0); acc := hres + b2 ----
        __syncthreads();                 // all phase-A hA/Wt reads done
        #pragma unroll
        for (int mt = 0; mt < 2; ++mt)
            #pragma unroll
            for (int nt = 0; nt < 4; ++nt) {
                float b2v = b2[wn * 64 + nt * 16 + l15];
                #pragma unroll
                for (int q = 0; q < 4; ++q) {
                    int row = wm * 32 + mt * 16 + g * 4 + q;
                    int col = wn * 64 + nt * 16 + l15;
                    int byte = row * 512 + ((col * 2) ^ ((row & 7) << 4));
                    float hres = bf2f(*(const unsigned short*)(hA + byte))
                               + bf2f(*(const unsigned short*)(hA + HA_LO + byte));
                    float a = fmaxf(acc[mt][nt][q] + tv[nt] + u0r[mt][nt][q], 0.f);
                    unsigned short hi = f2bf(a);
                    *(unsigned short*)(hA + byte) = hi;
                    *(unsigned short*)(hA + HA_LO + byte) = f2bf(a - bf2f(hi));
                    acc[mt][nt][q] = hres + b2v;       // phase-B accumulator init
                }
            }
        __syncthreads();                 // act visible

        // ---- phase B: acc += act @ W2 ----
        kloop<768>(WB, 0, 24, hA, Wt, acc, tid, wm, wn, l15, g);

        // ---- epilogue B: hnew = acc -> hA split ----
        __syncthreads();                 // all phase-B reads done
        #pragma unroll
        for (int mt = 0; mt < 2; ++mt)
            #pragma unroll
            for (int nt = 0; nt < 4; ++nt)
                #pragma unroll
                for (int q = 0; q < 4; ++q) {
                    int row = wm * 32 + mt * 16 + g * 4 + q;
                    int col = wn * 64 + nt * 16 + l15;
                    int byte = row * 512 + ((col * 2) ^ ((row & 7) << 4));
                    float hv = acc[mt][nt][q];
                    unsigned short hi = f2bf(hv);
                    *(unsigned short*)(hA + byte) = hi;
                    *(unsigned short*)(hA + HA_LO + byte) = f2bf(hv - bf2f(hi));
                    acc[mt][nt][q] = 0.f;
                }

        if (s < 3) {
            ST();                         // leading barrier covers hnew writes
            #pragma unroll
            for (int nt = 0; nt < 4; ++nt) {
                int col = wn * 64 + nt * 16 + l15;
                tv[nt] = Tp[col] + Tp[256 + col];
            }
        }
    }

    // ---- decoder: logits = h @ Wd + bd (B-frags direct from global/L2) ----
    __syncthreads();                     // hnew visible; Wt region free for Dp
    {
        const int rxA = (l15 & 7) << 4;
        const int rf = w & 3, kh2 = w >> 2;
        const int rowd = (rf * 16 + l15) * 512;
        f32x4 dacc = (f32x4){0.f, 0.f, 0.f, 0.f};
        #pragma unroll
        for (int t = 0; t < 12; ++t) {
            int kq = kh2 * 384 + t * 32;
            int reg = (kq >> 8) % 3;
            int aoff = (reg == 2) ? HA_LO : 0;
            int cb = (((kq & 255) * 2) + g * 16) ^ rxA;
            bf16x8 a = *(const bf16x8*)(hA + aoff + rowd + cb);
            bf16x8 bv = *(const bf16x8*)(WD + (size_t)l15 * 768 + kq + g * 8);
            dacc = __builtin_amdgcn_mfma_f32_16x16x32_bf16(a, bv, dacc, 0, 0, 0);
        }
        #pragma unroll
        for (int q = 0; q < 4; ++q)
            Dp[kh2 * 1024 + (rf * 16 + g * 4 + q) * 16 + l15] = dacc[q];
    }
    __syncthreads();
    #pragma unroll
    for (int e = 0; e < 2; ++e) {
        int idx = e * 512 + tid;
        int r = idx >> 4, a = idx & 15;
        out[(rowbase + r) * NACT + a] = Dp[r * 16 + a] + Dp[1024 + r * 16 + a] + bd[a];
    }
}

extern "C" void kernel_launch(void* const* d_in, const int* in_sizes, int n_in,
                              void* d_out, int out_size, void* d_ws, size_t ws_size,
                              hipStream_t stream) {
    const int*   ids = (const int*)d_in[0];
    const float* emb = (const float*)d_in[1];
    const float* W1  = (const float*)d_in[2];
    const float* b1  = (const float*)d_in[3];
    const float* W2  = (const float*)d_in[4];
    const float* b2  = (const float*)d_in[5];
    const float* Wd  = (const float*)d_in[6];
    const float* bd  = (const float*)d_in[7];
    float* out = (float*)d_out;

    char* p = (char*)d_ws;
    unsigned short* WA = (unsigned short*)p; p += (size_t)NWA * 2;
    unsigned short* WB = (unsigned short*)p; p += (size_t)NWB * 2;
    unsigned short* WD = (unsigned short*)p; p += (size_t)NWD * 2;
    float* Wc = (float*)p;

    prep_k<<<(NWA + NWB + NWD + NWC + 255) / 256, 256, 0, stream>>>(W1, W2, Wd, WA, WB, WD, Wc);
    fused_all<<<NB, 512, 0, stream>>>(ids, emb, WA, WB, WD, Wc, b1, b2, bd, out);
}

// Round 7
// 381.054 us; speedup vs baseline: 4.0937x; 4.0937x over previous
//
#include <hip/hip_runtime.h>

#define HID 256
#define NB 1024
#define NACT 16

typedef __bf16 bf16x8 __attribute__((ext_vector_type(8)));
typedef float  f32x4  __attribute__((ext_vector_type(4)));

// LDS map: hA 64 KB | two 32 KB weight tiles (BK=64). Total 128 KB, 1 block/CU.
#define HA_LO   32768
#define WT0_OFF 65536
#define WT1_OFF 98304
#define LDS_TOT 131072
// overlays in WT0 region (live only between kloops):
//   Sp f32[1024] @WT0 ; Sf f32[256] @WT0+4096 ; Tp f32[512] @WT0+8192
//   Dp f32[2048] @WT0 (decoder partials)

#define NWA (256*1536)
#define NWB (256*768)
#define NWD (16*768)
#define NWC (256*256)

__device__ __forceinline__ void gload_lds16(const void* g, void* l) {
    __builtin_amdgcn_global_load_lds(
        (const __attribute__((address_space(1))) void*)g,
        (__attribute__((address_space(3))) void*)l, 16, 0, 0);
}
__device__ __forceinline__ unsigned short f2bf(float x) {
    union { float f; unsigned u; } v; v.f = x;
    unsigned r = v.u + 0x7fff + ((v.u >> 16) & 1);
    return (unsigned short)(r >> 16);
}
__device__ __forceinline__ float bf2f(unsigned short b) {
    union { float f; unsigned u; } v; v.u = ((unsigned)b) << 16;
    return v.f;
}

// ---- prep: WA[256][1536]=[W1h0 stack|Aw stack]; WB[256][768]=W2 stack;
//            WD[16][768]=Wd stack; Wc f32 = inv*W1c ----
__global__ __launch_bounds__(256) void prep_k(const float* __restrict__ W1,
                                              const float* __restrict__ W2,
                                              const float* __restrict__ Wd,
                                              unsigned short* __restrict__ WA,
                                              unsigned short* __restrict__ WB,
                                              unsigned short* __restrict__ WD,
                                              float* __restrict__ Wc) {
    int i = blockIdx.x * 256 + threadIdx.x;
    const float inv = 1.0f / 63.0f;
    if (i < NWA) {
        int n = i / 1536, k = i % 1536;
        float val; int r;
        if (k < 768) { r = k >> 8; int ks = k & 255; val = W1[(512 + ks) * HID + n]; }
        else { int kk = k - 768; r = kk >> 8; int ks = kk & 255;
               val = W1[ks * HID + n] - inv * W1[(256 + ks) * HID + n]; }
        unsigned short hi = f2bf(val);
        WA[i] = (r == 1) ? f2bf(val - bf2f(hi)) : hi;
    } else if (i < NWA + NWB) {
        int j = i - NWA;
        int n = j / 768, k = j % 768;
        int r = k >> 8, ks = k & 255;
        float val = W2[ks * HID + n];
        unsigned short hi = f2bf(val);
        WB[j] = (r == 1) ? f2bf(val - bf2f(hi)) : hi;
    } else if (i < NWA + NWB + NWD) {
        int j = i - NWA - NWB;
        int n = j / 768, kp = j % 768;
        int r = kp >> 8, ks = kp & 255;
        float val = Wd[ks * NACT + n];
        unsigned short hi = f2bf(val);
        WD[j] = (r == 1) ? f2bf(val - bf2f(hi)) : hi;
    } else {
        int j = i - NWA - NWB - NWD;
        if (j < NWC) {
            int k = j >> 8, n = j & 255;
            Wc[j] = inv * W1[(256 + k) * HID + n];
        }
    }
}

// ---- double-buffered BK=64 K-loop via global_load_lds (T3-min 2-phase) ----
// Weight tile [256 n][64 k] bf16, row = 128 B = 8 slots; slot swizzle s^(n&7).
template<int LD>
__device__ __forceinline__ void kloopDB(const unsigned short* __restrict__ W,
                                        int kstart, int nk, char* lds,
                                        f32x4 (&acc)[2][4],
                                        int tid, int wm, int wn, int l15, int g)
{
    char* hA = lds;
    const int rxA = (l15 & 7) << 4;
    const int rowA0 = (wm * 32 + l15) * 512;
    const int rowA1 = rowA0 + 16 * 512;

    __syncthreads();                       // WT region free; prior hA writes visible
    #pragma unroll
    for (int p = 0; p < 4; ++p) {          // stage tile 0 -> buf0
        int c = p * 512 + tid;
        int n = c >> 3, sl = c & 7;
        int sp = sl ^ (n & 7);
        gload_lds16(W + (size_t)n * LD + kstart + sp * 8, lds + WT0_OFF + c * 16);
    }
    __syncthreads();                       // buf0 ready (barrier drains vmcnt)

    #pragma unroll 2
    for (int t = 0; t < nk; ++t) {
        const int cur = t & 1;
        if (t + 1 < nk) {                  // issue next tile BEFORE compute
            const int kk = kstart + (t + 1) * 64;
            char* dst = lds + (cur ? WT0_OFF : WT1_OFF);
            #pragma unroll
            for (int p = 0; p < 4; ++p) {
                int c = p * 512 + tid;
                int n = c >> 3, sl = c & 7;
                int sp = sl ^ (n & 7);
                gload_lds16(W + (size_t)n * LD + kk + sp * 8, dst + c * 16);
            }
        }
        const char* bb = lds + (cur ? WT1_OFF : WT0_OFF);
        const int k0 = kstart + t * 64;
        #pragma unroll
        for (int kh = 0; kh < 2; ++kh) {
            const int kq = k0 + kh * 32;
            const int reg = (kq >> 8) % 3;
            const int aoff = (reg == 2) ? HA_LO : 0;
            const int cb = (((kq & 255) * 2) + g * 16) ^ rxA;
            bf16x8 a0 = *(const bf16x8*)(hA + aoff + rowA0 + cb);
            bf16x8 a1 = *(const bf16x8*)(hA + aoff + rowA1 + cb);
            #pragma unroll
            for (int nt = 0; nt < 4; ++nt) {
                int nn = wn * 64 + nt * 16 + l15;
                int off = nn * 128 + ((((kh << 2) | g) ^ (nn & 7)) << 4);
                bf16x8 bv = *(const bf16x8*)(bb + off);
                acc[0][nt] = __builtin_amdgcn_mfma_f32_16x16x32_bf16(a0, bv, acc[0][nt], 0, 0, 0);
                acc[1][nt] = __builtin_amdgcn_mfma_f32_16x16x32_bf16(a1, bv, acc[1][nt], 0, 0, 0);
            }
        }
        __syncthreads();                   // drains t+1 loads; bb readers done
    }
}

// ---- S/T: T[n] = (sum_rows h) @ Wc  (all 512 threads; WT0 overlay) ----
__device__ __forceinline__ void STfun(char* lds, const float* __restrict__ Wc, int tid)
{
    char* hA = lds;
    float* Sp = (float*)(lds + WT0_OFF);
    float* Sf = (float*)(lds + WT0_OFF + 4096);
    float* Tp = (float*)(lds + WT0_OFF + 8192);
    __syncthreads();                 // hA writes visible; WT region free
    {
        int ww = tid & 127, gq = tid >> 7;
        float s0 = 0.f, s1 = 0.f;
        #pragma unroll 4
        for (int r = gq * 16; r < gq * 16 + 16; ++r) {
            int byte = r * 512 + ((ww * 4) ^ ((r & 7) << 4));
            unsigned vh = *(const unsigned*)(hA + byte);
            unsigned vl = *(const unsigned*)(hA + HA_LO + byte);
            s0 += bf2f((unsigned short)vh) + bf2f((unsigned short)vl);
            s1 += bf2f((unsigned short)(vh >> 16)) + bf2f((unsigned short)(vl >> 16));
        }
        Sp[gq * 256 + ww * 2] = s0;
        Sp[gq * 256 + ww * 2 + 1] = s1;
    }
    __syncthreads();
    if (tid < 256) Sf[tid] = (Sp[tid] + Sp[256 + tid]) + (Sp[512 + tid] + Sp[768 + tid]);
    __syncthreads();
    {
        int n = tid & 255, kh = tid >> 8;
        float a = 0.f;
        #pragma unroll 8
        for (int k = kh * 128; k < kh * 128 + 128; ++k)
            a += Sf[k] * Wc[(k << 8) + n];
        Tp[kh * 256 + n] = a;
    }
    __syncthreads();                 // Tp visible
}

// ---- whole network, one batch per block ----
__global__ __launch_bounds__(512, 2) void fused_all(
    const int* __restrict__ ids, const float* __restrict__ emb,
    const unsigned short* __restrict__ WA, const unsigned short* __restrict__ WB,
    const unsigned short* __restrict__ WD, const float* __restrict__ Wc,
    const float* __restrict__ b1, const float* __restrict__ b2,
    const float* __restrict__ bd, float* __restrict__ out)
{
    __shared__ __align__(16) char lds[LDS_TOT];
    const int tid = threadIdx.x;
    const int lane = tid & 63;
    const int w = tid >> 6;
    const int wm = w >> 2, wn = w & 3;
    const int l15 = lane & 15, g = lane >> 4;
    const size_t rowbase = (size_t)blockIdx.x * 64;
    char* hA = lds;
    float* Tp = (float*)(lds + WT0_OFF + 8192);
    float* Dp = (float*)(lds + WT0_OFF);

    // ---- stage h0 = emb[ids] -> split hi/lo, XOR-swizzled ----
    {
        int r = tid >> 3, c0 = (tid & 7) * 32;
        int rx = (r & 7) << 4;
        const float4* src = (const float4*)(emb + (size_t)ids[rowbase + r] * HID + c0);
        char* dh = hA + r * 512;
        #pragma unroll
        for (int j = 0; j < 8; ++j) {
            float4 v = src[j];
            unsigned short h0 = f2bf(v.x), h1 = f2bf(v.y), h2 = f2bf(v.z), h3 = f2bf(v.w);
            unsigned short q0 = f2bf(v.x - bf2f(h0)), q1 = f2bf(v.y - bf2f(h1)),
                           q2 = f2bf(v.z - bf2f(h2)), q3 = f2bf(v.w - bf2f(h3));
            int byte = ((c0 + j * 4) * 2) ^ rx;
            *(uint2*)(dh + byte) = make_uint2((unsigned)h0 | ((unsigned)h1 << 16),
                                             (unsigned)h2 | ((unsigned)h3 << 16));
            *(uint2*)(dh + HA_LO + byte) = make_uint2((unsigned)q0 | ((unsigned)q1 << 16),
                                                      (unsigned)q2 | ((unsigned)q3 << 16));
        }
    }

    // per-thread bias regs
    float b1r[4], b2r[4];
    #pragma unroll
    for (int nt = 0; nt < 4; ++nt) {
        int col = wn * 64 + nt * 16 + l15;
        b1r[nt] = b1[col];
        b2r[nt] = b2[col];
    }

    STfun(lds, Wc, tid);
    float tvr[4];
    #pragma unroll
    for (int nt = 0; nt < 4; ++nt) {
        int col = wn * 64 + nt * 16 + l15;
        tvr[nt] = Tp[col] + Tp[256 + col];
    }

    f32x4 acc[2][4], u0r[2][4];
    #pragma unroll
    for (int mt = 0; mt < 2; ++mt)
        #pragma unroll
        for (int nt = 0; nt < 4; ++nt) acc[mt][nt] = (f32x4){0.f, 0.f, 0.f, 0.f};

    for (int s = 0; s < 4; ++s) {
        if (s == 0) {
            // u0 = h0 @ W1h0 + b1 (acc starts 0)
            kloopDB<1536>(WA, 0, 12, lds, acc, tid, wm, wn, l15, g);
            #pragma unroll
            for (int mt = 0; mt < 2; ++mt)
                #pragma unroll
                for (int nt = 0; nt < 4; ++nt)
                    #pragma unroll
                    for (int q = 0; q < 4; ++q) {
                        u0r[mt][nt][q] = acc[mt][nt][q] + b1r[nt];
                        acc[mt][nt][q] = 0.f;
                    }
        }
        // acc init = T + u0, then acc += h @ Aw
        #pragma unroll
        for (int mt = 0; mt < 2; ++mt)
            #pragma unroll
            for (int nt = 0; nt < 4; ++nt)
                #pragma unroll
                for (int q = 0; q < 4; ++q)
                    acc[mt][nt][q] = tvr[nt] + u0r[mt][nt][q];
        kloopDB<1536>(WA, 768, 12, lds, acc, tid, wm, wn, l15, g);

        // epilogue A: act = relu(acc) -> hA ; acc := hres + b2
        #pragma unroll
        for (int mt = 0; mt < 2; ++mt)
            #pragma unroll
            for (int nt = 0; nt < 4; ++nt)
                #pragma unroll
                for (int q = 0; q < 4; ++q) {
                    int row = wm * 32 + mt * 16 + g * 4 + q;
                    int col = wn * 64 + nt * 16 + l15;
                    int byte = row * 512 + ((col * 2) ^ ((row & 7) << 4));
                    float hres = bf2f(*(const unsigned short*)(hA + byte))
                               + bf2f(*(const unsigned short*)(hA + HA_LO + byte));
                    float a = fmaxf(acc[mt][nt][q], 0.f);
                    unsigned short hi = f2bf(a);
                    *(unsigned short*)(hA + byte) = hi;
                    *(unsigned short*)(hA + HA_LO + byte) = f2bf(a - bf2f(hi));
                    acc[mt][nt][q] = hres + b2r[nt];
                }

        // phase B: acc += act @ W2   (kloop's leading barrier publishes act)
        kloopDB<768>(WB, 0, 12, lds, acc, tid, wm, wn, l15, g);

        // epilogue B: hnew = acc -> hA
        #pragma unroll
        for (int mt = 0; mt < 2; ++mt)
            #pragma unroll
            for (int nt = 0; nt < 4; ++nt)
                #pragma unroll
                for (int q = 0; q < 4; ++q) {
                    int row = wm * 32 + mt * 16 + g * 4 + q;
                    int col = wn * 64 + nt * 16 + l15;
                    int byte = row * 512 + ((col * 2) ^ ((row & 7) << 4));
                    float hv = acc[mt][nt][q];
                    unsigned short hi = f2bf(hv);
                    *(unsigned short*)(hA + byte) = hi;
                    *(unsigned short*)(hA + HA_LO + byte) = f2bf(hv - bf2f(hi));
                    acc[mt][nt][q] = 0.f;
                }

        if (s < 3) {
            STfun(lds, Wc, tid);          // leading barrier covers hnew writes
            #pragma unroll
            for (int nt = 0; nt < 4; ++nt) {
                int col = wn * 64 + nt * 16 + l15;
                tvr[nt] = Tp[col] + Tp[256 + col];
            }
        }
    }

    // ---- decoder: logits = h @ Wd + bd (B-frags direct from global/L2) ----
    __syncthreads();                     // hnew visible; WT region free for Dp
    {
        const int rxA = (l15 & 7) << 4;
        const int rf = w & 3, kh2 = w >> 2;
        const int rowd = (rf * 16 + l15) * 512;
        f32x4 dacc = (f32x4){0.f, 0.f, 0.f, 0.f};
        #pragma unroll
        for (int t = 0; t < 12; ++t) {
            int kq = kh2 * 384 + t * 32;
            int reg = (kq >> 8) % 3;
            int aoff = (reg == 2) ? HA_LO : 0;
            int cb = (((kq & 255) * 2) + g * 16) ^ rxA;
            bf16x8 a = *(const bf16x8*)(hA + aoff + rowd + cb);
            bf16x8 bv = *(const bf16x8*)(WD + (size_t)l15 * 768 + kq + g * 8);
            dacc = __builtin_amdgcn_mfma_f32_16x16x32_bf16(a, bv, dacc, 0, 0, 0);
        }
        #pragma unroll
        for (int q = 0; q < 4; ++q)
            Dp[kh2 * 1024 + (rf * 16 + g * 4 + q) * 16 + l15] = dacc[q];
    }
    __syncthreads();
    #pragma unroll
    for (int e = 0; e < 2; ++e) {
        int idx = e * 512 + tid;
        int r = idx >> 4, a = idx & 15;
        out[(rowbase + r) * NACT + a] = Dp[r * 16 + a] + Dp[1024 + r * 16 + a] + bd[a];
    }
}

extern "C" void kernel_launch(void* const* d_in, const int* in_sizes, int n_in,
                              void* d_out, int out_size, void* d_ws, size_t ws_size,
                              hipStream_t stream) {
    const int*   ids = (const int*)d_in[0];
    const float* emb = (const float*)d_in[1];
    const float* W1  = (const float*)d_in[2];
    const float* b1  = (const float*)d_in[3];
    const float* W2  = (const float*)d_in[4];
    const float* b2  = (const float*)d_in[5];
    const float* Wd  = (const float*)d_in[6];
    const float* bd  = (const float*)d_in[7];
    float* out = (float*)d_out;

    char* p = (char*)d_ws;
    unsigned short* WA = (unsigned short*)p; p += (size_t)NWA * 2;
    unsigned short* WB = (unsigned short*)p; p += (size_t)NWB * 2;
    unsigned short* WD = (unsigned short*)p; p += (size_t)NWD * 2;
    float* Wc = (float*)p;

    prep_k<<<(NWA + NWB + NWD + NWC + 255) / 256, 256, 0, stream>>>(W1, W2, Wd, WA, WB, WD, Wc);
    fused_all<<<NB, 512, 0, stream>>>(ids, emb, WA, WB, WD, Wc, b1, b2, bd, out);
}